// Round 2
// baseline (622.078 us; speedup 1.0000x reference)
//
#include <hip/hip_runtime.h>

// Decoder_33208687133135 — fused Koopman decoder, MI355X (gfx950).
// Only the diagonal of s,t survives -> layer4 is a per-row dot with one W4
// column. ~292 GFLOP total, compute-bound -> f16 MFMA (verified absmax
// 0.0625 vs threshold 0.2425 in R1).
//
// R1 post-mortem: pack_weights wrote 2.36 MB into d_ws WITHOUT checking
// ws_size -> OOB writes corrupted adjacent harness allocations (pristine
// input copies), making launch #1 correct but every post-restore launch
// consistently wrong. Fix: host-side guard on ws_size (launch-invariant,
// graph-capture safe). Fallback path reads fp32 weights directly from d_in
// and converts during LDS staging (no workspace use at all).

typedef _Float16 f16;
typedef _Float16 f16x8 __attribute__((ext_vector_type(8)));
typedef float f32x4 __attribute__((ext_vector_type(4)));

#define WPACK_PER_NET 589824
#define OFF_W1 0
#define OFF_W2 32768
#define OFF_W3 294912
#define OFF_W4T 557056
#define WPACK_BYTES (2u * WPACK_PER_NET * sizeof(f16))  // 2.36 MB

// ---------------- prologue: pack weights fp32 -> f16 blocked -------------
// B-fragment (16x16x32): B[k][n] held as n=lane&15, k=8*(lane>>4)+j.
// Blocked flat index: ((kk*32 + nt)*64 + (n&15) + 16*((k>>3)&3))*8 + (k&7).
__global__ void pack_weights(const float* __restrict__ sW1, const float* __restrict__ sW2,
                             const float* __restrict__ sW3, const float* __restrict__ sW4,
                             const float* __restrict__ tW1, const float* __restrict__ tW2,
                             const float* __restrict__ tW3, const float* __restrict__ tW4,
                             f16* __restrict__ dst) {
  int idx = blockIdx.x * 256 + threadIdx.x;
  if (idx >= 2 * WPACK_PER_NET) return;
  int net = idx >= WPACK_PER_NET;
  int f = idx - net * WPACK_PER_NET;
  const float* W1 = net ? tW1 : sW1;
  const float* W2 = net ? tW2 : sW2;
  const float* W3 = net ? tW3 : sW3;
  const float* W4 = net ? tW4 : sW4;
  float v;
  if (f < OFF_W2) {               // W1: (64,512)
    int j = f & 7, lane = (f >> 3) & 63, nt = (f >> 9) & 31, kk = f >> 14;
    v = W1[(kk * 32 + (lane >> 4) * 8 + j) * 512 + nt * 16 + (lane & 15)];
  } else if (f < OFF_W3) {        // W2: (512,512)
    int f2 = f - OFF_W2;
    int j = f2 & 7, lane = (f2 >> 3) & 63, nt = (f2 >> 9) & 31, kk = f2 >> 14;
    v = W2[(kk * 32 + (lane >> 4) * 8 + j) * 512 + nt * 16 + (lane & 15)];
  } else if (f < OFF_W4T) {       // W3: (512,512)
    int f3 = f - OFF_W3;
    int j = f3 & 7, lane = (f3 >> 3) & 63, nt = (f3 >> 9) & 31, kk = f3 >> 14;
    v = W3[(kk * 32 + (lane >> 4) * 8 + j) * 512 + nt * 16 + (lane & 15)];
  } else {                        // W4: (512,64) -> W4T[i][k]
    int f4 = f - OFF_W4T;
    v = W4[(f4 & 511) * 64 + (f4 >> 9)];
  }
  dst[net * WPACK_PER_NET + f] = (f16)v;
}

// A-fragment order index for activation element (m,k):
// chunk = (k>>5)*4 + (m>>4); lane = (m&15) + 16*((k>>3)&3); j = k&7.
__device__ __forceinline__ int aidx(int m, int k) {
  return (((k >> 5) * 4 + (m >> 4)) * 64 + (m & 15) + ((k >> 3) & 3) * 16) * 8 + (k & 7);
}

// Eigen-style rational tanh: ~1e-6 abs error on [-8,8].
__device__ __forceinline__ float fast_tanh(float x) {
  x = fminf(7.99881172f, fmaxf(-7.99881172f, x));
  float x2 = x * x;
  float p = fmaf(x2, -2.76076847742355e-16f, 2.00018790482477e-13f);
  p = fmaf(p, x2, -8.60467152213735e-11f);
  p = fmaf(p, x2, 5.12229709037114e-08f);
  p = fmaf(p, x2, 1.48572235717979e-05f);
  p = fmaf(p, x2, 6.37261928875436e-04f);
  p = fmaf(p, x2, 4.89352455891786e-03f);
  p = x * p;
  float q = fmaf(x2, 1.19825839466702e-06f, 1.18534705686654e-04f);
  q = fmaf(q, x2, 2.26843463243900e-03f);
  q = fmaf(q, x2, 4.89352518554385e-03f);
  return p * __builtin_amdgcn_rcpf(q);
}

// One MLP layer: Hout(64x512) = tanh(Asrc(64xK) @ W(Kx512) + bias).
// Wave w owns output cols [64w,64w+64).
// PACKED: W from f16 fragment-blocked wpack, double-buffered + reg prefetch.
// DIRECT: W from fp32 row-major d_in, single-buffered, convert on stage.
template <int NS, bool PACKED>
__device__ __forceinline__ void mlp_layer(const f16* __restrict__ Wblk,
                                          const float* __restrict__ Wraw,
                                          const float* __restrict__ bias,
                                          const f16* Asrc, f16* Hout,
                                          f16* WS0, f16* WS1,
                                          int t, int wave, int lane) {
  f32x4 acc[4][4];
#pragma unroll
  for (int nt = 0; nt < 4; nt++) {
    float bv = bias[wave * 64 + nt * 16 + (lane & 15)];
#pragma unroll
    for (int mt = 0; mt < 4; mt++) acc[mt][nt] = f32x4{bv, bv, bv, bv};
  }

  if (PACKED) {  // stage slice 0
    const uint4* g = (const uint4*)Wblk;
    uint4* s = (uint4*)WS0;
#pragma unroll
    for (int i = 0; i < 4; i++) s[t + 512 * i] = g[t + 512 * i];
    __syncthreads();
  }

  for (int kk = 0; kk < NS; kk++) {
    uint4 pre[4];
    if (PACKED) {
      if (kk + 1 < NS) {  // prefetch next slice into registers
        const uint4* g = (const uint4*)(Wblk + (kk + 1) * 16384);
#pragma unroll
        for (int i = 0; i < 4; i++) pre[i] = g[t + 512 * i];
      }
    } else {
      if (kk > 0) __syncthreads();  // previous compute done reading WS0
      // coalesced fp32 rows -> f16 fragment scatter
#pragma unroll
      for (int i = 0; i < 32; i++) {
        float v = Wraw[(kk * 32 + i) * 512 + t];
        WS0[((t >> 4) * 64 + (t & 15) + ((i >> 3) & 3) * 16) * 8 + (i & 7)] = (f16)v;
      }
      __syncthreads();
    }

    const f16* Wcur = PACKED ? ((kk & 1) ? WS1 : WS0) : WS0;
    f16x8 a[4], b[4];
#pragma unroll
    for (int mt = 0; mt < 4; mt++)
      a[mt] = *(const f16x8*)&Asrc[((kk * 4 + mt) * 64 + lane) * 8];
#pragma unroll
    for (int nt = 0; nt < 4; nt++)
      b[nt] = *(const f16x8*)&Wcur[((wave * 4 + nt) * 64 + lane) * 8];
#pragma unroll
    for (int mt = 0; mt < 4; mt++)
#pragma unroll
      for (int nt = 0; nt < 4; nt++)
        acc[mt][nt] =
            __builtin_amdgcn_mfma_f32_16x16x32_f16(a[mt], b[nt], acc[mt][nt], 0, 0, 0);

    if (PACKED) {
      if (kk + 1 < NS) {
        uint4* s = (uint4*)((kk & 1) ? WS0 : WS1);
#pragma unroll
        for (int i = 0; i < 4; i++) s[t + 512 * i] = pre[i];
      }
      __syncthreads();
    }
  }
  if (!PACKED) __syncthreads();  // all waves done reading Asrc (aliases Hout)

  // C/D layout (m89/m91): col = lane&15, row = (lane>>4)*4 + reg.
#pragma unroll
  for (int mt = 0; mt < 4; mt++)
#pragma unroll
    for (int nt = 0; nt < 4; nt++) {
      int col = wave * 64 + nt * 16 + (lane & 15);
#pragma unroll
      for (int r = 0; r < 4; r++) {
        int row = mt * 16 + (lane >> 4) * 4 + r;
        Hout[aidx(row, col)] = (f16)fast_tanh(acc[mt][nt][r]);
      }
    }
  __syncthreads();
}

template <bool PACKED>
__global__ __launch_bounds__(512, 2) void decoder_main(
    const float* __restrict__ x, const float* __restrict__ koop,
    const f16* __restrict__ wpack,
    const float* __restrict__ sW1, const float* __restrict__ sW2,
    const float* __restrict__ sW3, const float* __restrict__ sW4,
    const float* __restrict__ tW1, const float* __restrict__ tW2,
    const float* __restrict__ tW3, const float* __restrict__ tW4,
    const float* __restrict__ sb1, const float* __restrict__ sb2,
    const float* __restrict__ sb3, const float* __restrict__ sb4,
    const float* __restrict__ tb1, const float* __restrict__ tb2,
    const float* __restrict__ tb3, const float* __restrict__ tb4,
    float* __restrict__ out) {
  __shared__ __align__(16) f16 ZA[4096];          // z tile, A-frag order (8 KB)
  __shared__ __align__(16) f16 HA[32768];         // activations (64 KB)
  __shared__ __align__(16) f16 WSbuf[2][16384];   // weight slices (2x32 KB)
  __shared__ float redBuf[2][64];                 // ds, dt

  const int b = blockIdx.x;
  const int t = threadIdx.x;
  const int wave = t >> 6, lane = t & 63;

  // Stage z = koopman[b]^T as f16 A-fragments: z[d][l] = koop[b][l][d].
  const float* kb = koop + b * 4096;
#pragma unroll
  for (int i = 0; i < 8; i++) {
    int flat = t + 512 * i;                 // coalesced fp32 read
    ZA[aidx(flat & 63, flat >> 6)] = (f16)kb[flat];
  }
  if (!PACKED) __syncthreads();  // DIRECT layer1 has no pre-read barrier

  for (int net = 0; net < 2; net++) {
    const f16* wb = PACKED ? (wpack + net * WPACK_PER_NET) : (const f16*)0;
    const float* W1 = net ? tW1 : sW1;
    const float* W2 = net ? tW2 : sW2;
    const float* W3 = net ? tW3 : sW3;
    const float* W4 = net ? tW4 : sW4;
    const float* b1 = net ? tb1 : sb1;
    const float* b2 = net ? tb2 : sb2;
    const float* b3 = net ? tb3 : sb3;
    const float* b4 = net ? tb4 : sb4;
    mlp_layer<2, PACKED>(PACKED ? wb + OFF_W1 : 0, W1, b1, ZA, HA,
                         WSbuf[0], WSbuf[1], t, wave, lane);
    mlp_layer<16, PACKED>(PACKED ? wb + OFF_W2 : 0, W2, b2, HA, HA,
                          WSbuf[0], WSbuf[1], t, wave, lane);
    mlp_layer<16, PACKED>(PACKED ? wb + OFF_W3 : 0, W3, b3, HA, HA,
                          WSbuf[0], WSbuf[1], t, wave, lane);

    // Diagonal epilogue: ds[i] = H3[i,:] . W4[:,i] + b4[i].
    int i = t >> 3, sub = t & 7;  // 8 threads per row
    float p = 0.f;
#pragma unroll
    for (int q = 0; q < 8; q++) {
      int k0 = sub * 64 + q * 8;
      f16x8 hv = *(const f16x8*)&HA[aidx(i, k0)];
      if (PACKED) {
        f16x8 wv = *(const f16x8*)&wb[OFF_W4T + i * 512 + k0];
#pragma unroll
        for (int j = 0; j < 8; j++) p += (float)hv[j] * (float)wv[j];
      } else {
#pragma unroll
        for (int j = 0; j < 8; j++) p += (float)hv[j] * W4[(k0 + j) * 64 + i];
      }
    }
    p += __shfl_down(p, 4, 8);
    p += __shfl_down(p, 2, 8);
    p += __shfl_down(p, 1, 8);
    if (sub == 0) redBuf[net][i] = p + b4[i];
    __syncthreads();
  }

  if (t < 64) {
    out[b * 64 + t] = (x[b * 64 + t] - redBuf[1][t]) * __expf(-redBuf[0][t]);
  }
}

extern "C" void kernel_launch(void* const* d_in, const int* in_sizes, int n_in,
                              void* d_out, int out_size, void* d_ws, size_t ws_size,
                              hipStream_t stream) {
  const float* x    = (const float*)d_in[0];
  const float* koop = (const float*)d_in[1];
  const float* sW1 = (const float*)d_in[2];  const float* sb1 = (const float*)d_in[3];
  const float* sW2 = (const float*)d_in[4];  const float* sb2 = (const float*)d_in[5];
  const float* sW3 = (const float*)d_in[6];  const float* sb3 = (const float*)d_in[7];
  const float* sW4 = (const float*)d_in[8];  const float* sb4 = (const float*)d_in[9];
  const float* tW1 = (const float*)d_in[10]; const float* tb1 = (const float*)d_in[11];
  const float* tW2 = (const float*)d_in[12]; const float* tb2 = (const float*)d_in[13];
  const float* tW3 = (const float*)d_in[14]; const float* tb3 = (const float*)d_in[15];
  const float* tW4 = (const float*)d_in[16]; const float* tb4 = (const float*)d_in[17];
  float* out = (float*)d_out;

  // Launch-invariant branch (ws_size is constant across calls) -> safe for
  // graph capture. NEVER write past ws_size (R1: OOB pack corrupted the
  // harness's pristine input copies).
  if (ws_size >= (size_t)WPACK_BYTES) {
    f16* wpack = (f16*)d_ws;
    pack_weights<<<4608, 256, 0, stream>>>(sW1, sW2, sW3, sW4, tW1, tW2, tW3, tW4, wpack);
    decoder_main<true><<<2048, 512, 0, stream>>>(
        x, koop, wpack, sW1, sW2, sW3, sW4, tW1, tW2, tW3, tW4,
        sb1, sb2, sb3, sb4, tb1, tb2, tb3, tb4, out);
  } else {
    decoder_main<false><<<2048, 512, 0, stream>>>(
        x, koop, (const f16*)0, sW1, sW2, sW3, sW4, tW1, tW2, tW3, tW4,
        sb1, sb2, sb3, sb4, tb1, tb2, tb3, tb4, out);
  }
}

// Round 3
// 455.083 us; speedup vs baseline: 1.3670x; 1.3670x over previous
//
#include <hip/hip_runtime.h>

// Decoder_33208687133135 — fused Koopman decoder, MI355X (gfx950).
// Only the diagonal of s,t survives -> layer4 is a per-row dot with one W4
// column. ~292 GFLOP, f16 MFMA (absmax 0.0625 vs thr 0.2425, R1/R2).
//
// R2 post-mortem: 604 us, MfmaUtil 21%, Occupancy 23% -> 1 WG/CU (136.5 KB
// LDS) with ~70 fully-exposed barriers/WG from LDS weight staging. Staging
// weights via LDS does NOT reduce L2 traffic (each weight byte feeds exactly
// one wave). R3: read B-fragments straight from the packed L2-resident
// buffer into VGPRs (depth-1 register prefetch, no barriers), drop both
// weight LDS buffers -> 72.5 KB LDS -> 2 WG/CU, 15 barriers/WG.

typedef _Float16 f16;
typedef _Float16 f16x8 __attribute__((ext_vector_type(8)));
typedef float f32x4 __attribute__((ext_vector_type(4)));

#define WPACK_PER_NET 589824
#define OFF_W1 0
#define OFF_W2 32768
#define OFF_W3 294912
#define OFF_W4T 557056
#define WPACK_BYTES (2u * WPACK_PER_NET * sizeof(f16))  // 2.36 MB

// ---------------- prologue: pack weights fp32 -> f16 blocked -------------
// B-fragment (16x16x32): B[k][n] held as n=lane&15, k=8*(lane>>4)+j.
// Blocked flat index: ((kk*32 + nt)*64 + (n&15) + 16*((k>>3)&3))*8 + (k&7).
__global__ void pack_weights(const float* __restrict__ sW1, const float* __restrict__ sW2,
                             const float* __restrict__ sW3, const float* __restrict__ sW4,
                             const float* __restrict__ tW1, const float* __restrict__ tW2,
                             const float* __restrict__ tW3, const float* __restrict__ tW4,
                             f16* __restrict__ dst) {
  int idx = blockIdx.x * 256 + threadIdx.x;
  if (idx >= 2 * WPACK_PER_NET) return;
  int net = idx >= WPACK_PER_NET;
  int f = idx - net * WPACK_PER_NET;
  const float* W1 = net ? tW1 : sW1;
  const float* W2 = net ? tW2 : sW2;
  const float* W3 = net ? tW3 : sW3;
  const float* W4 = net ? tW4 : sW4;
  float v;
  if (f < OFF_W2) {               // W1: (64,512)
    int j = f & 7, lane = (f >> 3) & 63, nt = (f >> 9) & 31, kk = f >> 14;
    v = W1[(kk * 32 + (lane >> 4) * 8 + j) * 512 + nt * 16 + (lane & 15)];
  } else if (f < OFF_W3) {        // W2: (512,512)
    int f2 = f - OFF_W2;
    int j = f2 & 7, lane = (f2 >> 3) & 63, nt = (f2 >> 9) & 31, kk = f2 >> 14;
    v = W2[(kk * 32 + (lane >> 4) * 8 + j) * 512 + nt * 16 + (lane & 15)];
  } else if (f < OFF_W4T) {       // W3: (512,512)
    int f3 = f - OFF_W3;
    int j = f3 & 7, lane = (f3 >> 3) & 63, nt = (f3 >> 9) & 31, kk = f3 >> 14;
    v = W3[(kk * 32 + (lane >> 4) * 8 + j) * 512 + nt * 16 + (lane & 15)];
  } else {                        // W4: (512,64) -> W4T[i][k]
    int f4 = f - OFF_W4T;
    v = W4[(f4 & 511) * 64 + (f4 >> 9)];
  }
  dst[net * WPACK_PER_NET + f] = (f16)v;
}

// A-fragment order index for activation element (m,k):
// chunk = (k>>5)*4 + (m>>4); lane = (m&15) + 16*((k>>3)&3); j = k&7.
__device__ __forceinline__ int aidx(int m, int k) {
  return (((k >> 5) * 4 + (m >> 4)) * 64 + (m & 15) + ((k >> 3) & 3) * 16) * 8 + (k & 7);
}

// Eigen-style rational tanh: ~1e-6 abs error on [-8,8].
__device__ __forceinline__ float fast_tanh(float x) {
  x = fminf(7.99881172f, fmaxf(-7.99881172f, x));
  float x2 = x * x;
  float p = fmaf(x2, -2.76076847742355e-16f, 2.00018790482477e-13f);
  p = fmaf(p, x2, -8.60467152213735e-11f);
  p = fmaf(p, x2, 5.12229709037114e-08f);
  p = fmaf(p, x2, 1.48572235717979e-05f);
  p = fmaf(p, x2, 6.37261928875436e-04f);
  p = fmaf(p, x2, 4.89352455891786e-03f);
  p = x * p;
  float q = fmaf(x2, 1.19825839466702e-06f, 1.18534705686654e-04f);
  q = fmaf(q, x2, 2.26843463243900e-03f);
  q = fmaf(q, x2, 4.89352518554385e-03f);
  return p * __builtin_amdgcn_rcpf(q);
}

// Load the wave's 4 B-fragments for k-slice kk.
// PACKED: lane-contiguous 16B loads from the frag-blocked f16 buffer (L2).
// DIRECT: coalesced fp32 gather from row-major W, convert in regs.
template <bool PACKED>
__device__ __forceinline__ void load_b(const f16* __restrict__ Wblk,
                                       const float* __restrict__ Wraw,
                                       int kk, int wave, int lane, f16x8* bdst) {
  if (PACKED) {
#pragma unroll
    for (int nt = 0; nt < 4; nt++)
      bdst[nt] = *(const f16x8*)(Wblk + kk * 16384 + ((wave * 4 + nt) * 64 + lane) * 8);
  } else {
    int n0 = wave * 64 + (lane & 15);
    int kb = kk * 32 + (lane >> 4) * 8;
#pragma unroll
    for (int nt = 0; nt < 4; nt++) {
      f16x8 v;
#pragma unroll
      for (int j = 0; j < 8; j++) v[j] = (f16)Wraw[(kb + j) * 512 + n0 + nt * 16];
      bdst[nt] = v;
    }
  }
}

// One MLP layer: Hout(64x512) = tanh(Asrc(64xK) @ W(Kx512) + bias).
// Wave w owns output cols [64w,64w+64). Weights stream L2->VGPR, depth-1
// register prefetch; no weight LDS, no intra-loop barriers.
template <int NS, bool PACKED>
__device__ __forceinline__ void mlp_layer(const f16* __restrict__ Wblk,
                                          const float* __restrict__ Wraw,
                                          const float* __restrict__ bias,
                                          const f16* Asrc, f16* Hout,
                                          int t, int wave, int lane) {
  f32x4 acc[4][4];
#pragma unroll
  for (int nt = 0; nt < 4; nt++) {
    float bv = bias[wave * 64 + nt * 16 + (lane & 15)];
#pragma unroll
    for (int mt = 0; mt < 4; mt++) acc[mt][nt] = f32x4{bv, bv, bv, bv};
  }

  f16x8 bc[4], bn[4];
  load_b<PACKED>(Wblk, Wraw, 0, wave, lane, bc);
#pragma unroll
  for (int kk = 0; kk < NS; kk++) {
    if (kk + 1 < NS) load_b<PACKED>(Wblk, Wraw, kk + 1, wave, lane, bn);
    f16x8 a[4];
#pragma unroll
    for (int mt = 0; mt < 4; mt++)
      a[mt] = *(const f16x8*)&Asrc[((kk * 4 + mt) * 64 + lane) * 8];
#pragma unroll
    for (int mt = 0; mt < 4; mt++)
#pragma unroll
      for (int nt = 0; nt < 4; nt++)
        acc[mt][nt] =
            __builtin_amdgcn_mfma_f32_16x16x32_f16(a[mt], bc[nt], acc[mt][nt], 0, 0, 0);
    if (kk + 1 < NS) {
#pragma unroll
      for (int nt = 0; nt < 4; nt++) bc[nt] = bn[nt];
    }
  }
  __syncthreads();  // all waves done reading Asrc (may alias Hout)

  // C/D layout (m89/m91): col = lane&15, row = (lane>>4)*4 + reg.
#pragma unroll
  for (int mt = 0; mt < 4; mt++)
#pragma unroll
    for (int nt = 0; nt < 4; nt++) {
      int col = wave * 64 + nt * 16 + (lane & 15);
#pragma unroll
      for (int r = 0; r < 4; r++) {
        int row = mt * 16 + (lane >> 4) * 4 + r;
        Hout[aidx(row, col)] = (f16)fast_tanh(acc[mt][nt][r]);
      }
    }
  __syncthreads();
}

template <bool PACKED>
__global__ __launch_bounds__(512, 4) void decoder_main(
    const float* __restrict__ x, const float* __restrict__ koop,
    const f16* __restrict__ wpack,
    const float* __restrict__ sW1, const float* __restrict__ sW2,
    const float* __restrict__ sW3, const float* __restrict__ sW4,
    const float* __restrict__ tW1, const float* __restrict__ tW2,
    const float* __restrict__ tW3, const float* __restrict__ tW4,
    const float* __restrict__ sb1, const float* __restrict__ sb2,
    const float* __restrict__ sb3, const float* __restrict__ sb4,
    const float* __restrict__ tb1, const float* __restrict__ tb2,
    const float* __restrict__ tb3, const float* __restrict__ tb4,
    float* __restrict__ out) {
  __shared__ __align__(16) f16 ZA[4096];   // z tile, A-frag order (8 KB)
  __shared__ __align__(16) f16 HA[32768];  // activations (64 KB)
  __shared__ float redBuf[2][64];          // ds, dt
  // total 72.5 KB -> 2 WG/CU

  const int b = blockIdx.x;
  const int t = threadIdx.x;
  const int wave = t >> 6, lane = t & 63;

  // Stage z = koopman[b]^T as f16 A-fragments: z[d][l] = koop[b][l][d].
  const float* kb = koop + b * 4096;
#pragma unroll
  for (int i = 0; i < 8; i++) {
    int flat = t + 512 * i;                 // coalesced fp32 read
    ZA[aidx(flat & 63, flat >> 6)] = (f16)kb[flat];
  }
  __syncthreads();

  for (int net = 0; net < 2; net++) {
    const f16* wb = PACKED ? (wpack + net * WPACK_PER_NET) : (const f16*)0;
    const float* W1 = net ? tW1 : sW1;
    const float* W2 = net ? tW2 : sW2;
    const float* W3 = net ? tW3 : sW3;
    const float* W4 = net ? tW4 : sW4;
    const float* b1 = net ? tb1 : sb1;
    const float* b2 = net ? tb2 : sb2;
    const float* b3 = net ? tb3 : sb3;
    const float* b4 = net ? tb4 : sb4;
    mlp_layer<2, PACKED>(PACKED ? wb + OFF_W1 : 0, W1, b1, ZA, HA, t, wave, lane);
    mlp_layer<16, PACKED>(PACKED ? wb + OFF_W2 : 0, W2, b2, HA, HA, t, wave, lane);
    mlp_layer<16, PACKED>(PACKED ? wb + OFF_W3 : 0, W3, b3, HA, HA, t, wave, lane);

    // Diagonal epilogue: ds[i] = H3[i,:] . W4[:,i] + b4[i].
    int i = t >> 3, sub = t & 7;  // 8 threads per row
    float p = 0.f;
#pragma unroll
    for (int q = 0; q < 8; q++) {
      int k0 = sub * 64 + q * 8;
      f16x8 hv = *(const f16x8*)&HA[aidx(i, k0)];
      if (PACKED) {
        f16x8 wv = *(const f16x8*)&wb[OFF_W4T + i * 512 + k0];
#pragma unroll
        for (int j = 0; j < 8; j++) p += (float)hv[j] * (float)wv[j];
      } else {
#pragma unroll
        for (int j = 0; j < 8; j++) p += (float)hv[j] * W4[(k0 + j) * 64 + i];
      }
    }
    p += __shfl_down(p, 4, 8);
    p += __shfl_down(p, 2, 8);
    p += __shfl_down(p, 1, 8);
    if (sub == 0) redBuf[net][i] = p + b4[i];
    __syncthreads();
  }

  if (t < 64) {
    out[b * 64 + t] = (x[b * 64 + t] - redBuf[1][t]) * __expf(-redBuf[0][t]);
  }
}

extern "C" void kernel_launch(void* const* d_in, const int* in_sizes, int n_in,
                              void* d_out, int out_size, void* d_ws, size_t ws_size,
                              hipStream_t stream) {
  const float* x    = (const float*)d_in[0];
  const float* koop = (const float*)d_in[1];
  const float* sW1 = (const float*)d_in[2];  const float* sb1 = (const float*)d_in[3];
  const float* sW2 = (const float*)d_in[4];  const float* sb2 = (const float*)d_in[5];
  const float* sW3 = (const float*)d_in[6];  const float* sb3 = (const float*)d_in[7];
  const float* sW4 = (const float*)d_in[8];  const float* sb4 = (const float*)d_in[9];
  const float* tW1 = (const float*)d_in[10]; const float* tb1 = (const float*)d_in[11];
  const float* tW2 = (const float*)d_in[12]; const float* tb2 = (const float*)d_in[13];
  const float* tW3 = (const float*)d_in[14]; const float* tb3 = (const float*)d_in[15];
  const float* tW4 = (const float*)d_in[16]; const float* tb4 = (const float*)d_in[17];
  float* out = (float*)d_out;

  // Launch-invariant branch (ws_size constant across calls) -> graph-safe.
  // NEVER write past ws_size (R1: OOB pack corrupted harness allocations).
  if (ws_size >= (size_t)WPACK_BYTES) {
    f16* wpack = (f16*)d_ws;
    pack_weights<<<4608, 256, 0, stream>>>(sW1, sW2, sW3, sW4, tW1, tW2, tW3, tW4, wpack);
    decoder_main<true><<<2048, 512, 0, stream>>>(
        x, koop, wpack, sW1, sW2, sW3, sW4, tW1, tW2, tW3, tW4,
        sb1, sb2, sb3, sb4, tb1, tb2, tb3, tb4, out);
  } else {
    decoder_main<false><<<2048, 512, 0, stream>>>(
        x, koop, (const f16*)0, sW1, sW2, sW3, sW4, tW1, tW2, tW3, tW4,
        sb1, sb2, sb3, sb4, tb1, tb2, tb3, tb4, out);
  }
}

// Round 4
// 431.849 us; speedup vs baseline: 1.4405x; 1.0538x over previous
//
#include <hip/hip_runtime.h>

// Decoder_33208687133135 — fused Koopman decoder, MI355X (gfx950).
// Only the diagonal of s,t survives -> layer4 is a per-row dot with one W4
// column. ~292 GFLOP, f16 MFMA (absmax 0.0625 vs thr 0.2425).
//
// R3 post-mortem: 378 us, MfmaUtil 37%, Occ 42% (2 WG/CU, 4 waves/SIMD —
// structural max: acc=64 AGPR locks 128-reg budget). Largest real pipe cost
// is VALU: 14-inst rational tanh x384/lane + ~1.5k scatter-addr inst/lane.
// WRITE_SIZE=36MB (vs 0.5MB actual output) suggests scratch spill at the
// 64-arch-VGPR cap. R4: 6-inst exp-based tanh, hoisted scatter base with
// immediate offsets, alternating b-frag buffers (no copy -> lower liveness).

typedef _Float16 f16;
typedef _Float16 f16x8 __attribute__((ext_vector_type(8)));
typedef float f32x4 __attribute__((ext_vector_type(4)));

#define WPACK_PER_NET 589824
#define OFF_W1 0
#define OFF_W2 32768
#define OFF_W3 294912
#define OFF_W4T 557056
#define WPACK_BYTES (2u * WPACK_PER_NET * sizeof(f16))  // 2.36 MB

// ---------------- prologue: pack weights fp32 -> f16 blocked -------------
// B-fragment (16x16x32): B[k][n] held as n=lane&15, k=8*(lane>>4)+j.
// Blocked flat index: ((kk*32 + nt)*64 + (n&15) + 16*((k>>3)&3))*8 + (k&7).
__global__ void pack_weights(const float* __restrict__ sW1, const float* __restrict__ sW2,
                             const float* __restrict__ sW3, const float* __restrict__ sW4,
                             const float* __restrict__ tW1, const float* __restrict__ tW2,
                             const float* __restrict__ tW3, const float* __restrict__ tW4,
                             f16* __restrict__ dst) {
  int idx = blockIdx.x * 256 + threadIdx.x;
  if (idx >= 2 * WPACK_PER_NET) return;
  int net = idx >= WPACK_PER_NET;
  int f = idx - net * WPACK_PER_NET;
  const float* W1 = net ? tW1 : sW1;
  const float* W2 = net ? tW2 : sW2;
  const float* W3 = net ? tW3 : sW3;
  const float* W4 = net ? tW4 : sW4;
  float v;
  if (f < OFF_W2) {               // W1: (64,512)
    int j = f & 7, lane = (f >> 3) & 63, nt = (f >> 9) & 31, kk = f >> 14;
    v = W1[(kk * 32 + (lane >> 4) * 8 + j) * 512 + nt * 16 + (lane & 15)];
  } else if (f < OFF_W3) {        // W2: (512,512)
    int f2 = f - OFF_W2;
    int j = f2 & 7, lane = (f2 >> 3) & 63, nt = (f2 >> 9) & 31, kk = f2 >> 14;
    v = W2[(kk * 32 + (lane >> 4) * 8 + j) * 512 + nt * 16 + (lane & 15)];
  } else if (f < OFF_W4T) {       // W3: (512,512)
    int f3 = f - OFF_W3;
    int j = f3 & 7, lane = (f3 >> 3) & 63, nt = (f3 >> 9) & 31, kk = f3 >> 14;
    v = W3[(kk * 32 + (lane >> 4) * 8 + j) * 512 + nt * 16 + (lane & 15)];
  } else {                        // W4: (512,64) -> W4T[i][k]
    int f4 = f - OFF_W4T;
    v = W4[(f4 & 511) * 64 + (f4 >> 9)];
  }
  dst[net * WPACK_PER_NET + f] = (f16)v;
}

// A-fragment order index for activation element (m,k):
// chunk = (k>>5)*4 + (m>>4); lane = (m&15) + 16*((k>>3)&3); j = k&7.
__device__ __forceinline__ int aidx(int m, int k) {
  return (((k >> 5) * 4 + (m >> 4)) * 64 + (m & 15) + ((k >> 3) & 3) * 16) * 8 + (k & 7);
}

// tanh(x) = 1 - 2/(exp(2x)+1). 6 VALU inst (2 trans-pipe). Saturates
// correctly at +/-inf (exp->inf -> 1; exp->0 -> -1), no clamp needed.
__device__ __forceinline__ float fast_tanh(float x) {
  float e = __expf(x + x);                       // v_mul (log2e fold) + v_exp
  return fmaf(-2.0f, __builtin_amdgcn_rcpf(e + 1.0f), 1.0f);
}

// Load the wave's 4 B-fragments for k-slice kk.
// PACKED: lane-contiguous 16B loads from the frag-blocked f16 buffer (L2).
// DIRECT: coalesced fp32 gather from row-major W, convert in regs.
template <bool PACKED>
__device__ __forceinline__ void load_b(const f16* __restrict__ Wblk,
                                       const float* __restrict__ Wraw,
                                       int kk, int wave, int lane, f16x8* bdst) {
  if (PACKED) {
#pragma unroll
    for (int nt = 0; nt < 4; nt++)
      bdst[nt] = *(const f16x8*)(Wblk + kk * 16384 + ((wave * 4 + nt) * 64 + lane) * 8);
  } else {
    int n0 = wave * 64 + (lane & 15);
    int kb = kk * 32 + (lane >> 4) * 8;
#pragma unroll
    for (int nt = 0; nt < 4; nt++) {
      f16x8 v;
#pragma unroll
      for (int j = 0; j < 8; j++) v[j] = (f16)Wraw[(kb + j) * 512 + n0 + nt * 16];
      bdst[nt] = v;
    }
  }
}

// One MLP layer: Hout(64x512) = tanh(Asrc(64xK) @ W(Kx512) + bias).
// Wave w owns output cols [64w,64w+64). Weights stream L2->VGPR, depth-1
// alternating-buffer prefetch; no weight LDS, no intra-loop barriers.
// sbase: precomputed lane part of the C->A scatter index (see epilogue).
template <int NS, bool PACKED>
__device__ __forceinline__ void mlp_layer(const f16* __restrict__ Wblk,
                                          const float* __restrict__ Wraw,
                                          const float* __restrict__ bias,
                                          const f16* Asrc, f16* Hout,
                                          int wave, int lane, int sbase) {
  f32x4 acc[4][4];
#pragma unroll
  for (int nt = 0; nt < 4; nt++) {
    float bv = bias[wave * 64 + nt * 16 + (lane & 15)];
#pragma unroll
    for (int mt = 0; mt < 4; mt++) acc[mt][nt] = f32x4{bv, bv, bv, bv};
  }

  f16x8 bb[2][4];
  load_b<PACKED>(Wblk, Wraw, 0, wave, lane, bb[0]);
#pragma unroll
  for (int kk = 0; kk < NS; kk++) {
    if (kk + 1 < NS) load_b<PACKED>(Wblk, Wraw, kk + 1, wave, lane, bb[(kk + 1) & 1]);
    const f16* ab = Asrc + kk * 2048 + lane * 8;  // + const*512 per mt (imm)
    f16x8 a[4];
#pragma unroll
    for (int mt = 0; mt < 4; mt++) a[mt] = *(const f16x8*)(ab + mt * 512);
#pragma unroll
    for (int mt = 0; mt < 4; mt++)
#pragma unroll
      for (int nt = 0; nt < 4; nt++)
        acc[mt][nt] = __builtin_amdgcn_mfma_f32_16x16x32_f16(a[mt], bb[kk & 1][nt],
                                                             acc[mt][nt], 0, 0, 0);
  }
  __syncthreads();  // all waves done reading Asrc (may alias Hout)

  // C/D layout (m89/m91): col = wave*64 + nt*16 + (lane&15),
  // row = mt*16 + (lane>>4)*4 + r. Target A-frag elem index decomposes as
  // sbase(lane) + const(mt,nt,r)  [algebra verified vs aidx()]:
  //   sbase = wave*4096 + (lane>>4)*32 + ((lane&15)>>3)*128 + (lane&7)
  //   const = (nt>>1)*2048 + mt*512 + (nt&1)*256 + r*8
  // -> ds_write_b16 with immediate offsets, zero per-store address VALU.
  f16* hb = Hout + sbase;
#pragma unroll
  for (int mt = 0; mt < 4; mt++)
#pragma unroll
    for (int nt = 0; nt < 4; nt++)
#pragma unroll
      for (int r = 0; r < 4; r++)
        hb[(nt >> 1) * 2048 + mt * 512 + (nt & 1) * 256 + r * 8] =
            (f16)fast_tanh(acc[mt][nt][r]);
  __syncthreads();
}

template <bool PACKED>
__global__ __launch_bounds__(512, 4) void decoder_main(
    const float* __restrict__ x, const float* __restrict__ koop,
    const f16* __restrict__ wpack,
    const float* __restrict__ sW1, const float* __restrict__ sW2,
    const float* __restrict__ sW3, const float* __restrict__ sW4,
    const float* __restrict__ tW1, const float* __restrict__ tW2,
    const float* __restrict__ tW3, const float* __restrict__ tW4,
    const float* __restrict__ sb1, const float* __restrict__ sb2,
    const float* __restrict__ sb3, const float* __restrict__ sb4,
    const float* __restrict__ tb1, const float* __restrict__ tb2,
    const float* __restrict__ tb3, const float* __restrict__ tb4,
    float* __restrict__ out) {
  __shared__ __align__(16) f16 ZA[4096];   // z tile, A-frag order (8 KB)
  __shared__ __align__(16) f16 HA[32768];  // activations (64 KB)
  __shared__ float redBuf[2][64];          // ds, dt
  // total 72.5 KB -> 2 WG/CU

  const int b = blockIdx.x;
  const int t = threadIdx.x;
  const int wave = t >> 6, lane = t & 63;
  const int sbase =
      wave * 4096 + (lane >> 4) * 32 + ((lane & 15) >> 3) * 128 + (lane & 7);

  // Stage z = koopman[b]^T as f16 A-fragments: z[d][l] = koop[b][l][d].
  const float* kb = koop + b * 4096;
#pragma unroll
  for (int i = 0; i < 8; i++) {
    int flat = t + 512 * i;                 // coalesced fp32 read
    ZA[aidx(flat & 63, flat >> 6)] = (f16)kb[flat];
  }
  __syncthreads();

  for (int net = 0; net < 2; net++) {
    const f16* wb = PACKED ? (wpack + net * WPACK_PER_NET) : (const f16*)0;
    const float* W1 = net ? tW1 : sW1;
    const float* W2 = net ? tW2 : sW2;
    const float* W3 = net ? tW3 : sW3;
    const float* W4 = net ? tW4 : sW4;
    const float* b1 = net ? tb1 : sb1;
    const float* b2 = net ? tb2 : sb2;
    const float* b3 = net ? tb3 : sb3;
    const float* b4 = net ? tb4 : sb4;
    mlp_layer<2, PACKED>(PACKED ? wb + OFF_W1 : 0, W1, b1, ZA, HA, wave, lane, sbase);
    mlp_layer<16, PACKED>(PACKED ? wb + OFF_W2 : 0, W2, b2, HA, HA, wave, lane, sbase);
    mlp_layer<16, PACKED>(PACKED ? wb + OFF_W3 : 0, W3, b3, HA, HA, wave, lane, sbase);

    // Diagonal epilogue: ds[i] = H3[i,:] . W4[:,i] + b4[i].
    int i = t >> 3, sub = t & 7;  // 8 threads per row
    float p = 0.f;
#pragma unroll
    for (int q = 0; q < 8; q++) {
      int k0 = sub * 64 + q * 8;
      f16x8 hv = *(const f16x8*)&HA[aidx(i, k0)];
      if (PACKED) {
        f16x8 wv = *(const f16x8*)&wb[OFF_W4T + i * 512 + k0];
#pragma unroll
        for (int j = 0; j < 8; j++) p += (float)hv[j] * (float)wv[j];
      } else {
#pragma unroll
        for (int j = 0; j < 8; j++) p += (float)hv[j] * W4[(k0 + j) * 64 + i];
      }
    }
    p += __shfl_down(p, 4, 8);
    p += __shfl_down(p, 2, 8);
    p += __shfl_down(p, 1, 8);
    if (sub == 0) redBuf[net][i] = p + b4[i];
    __syncthreads();
  }

  if (t < 64) {
    out[b * 64 + t] = (x[b * 64 + t] - redBuf[1][t]) * __expf(-redBuf[0][t]);
  }
}

extern "C" void kernel_launch(void* const* d_in, const int* in_sizes, int n_in,
                              void* d_out, int out_size, void* d_ws, size_t ws_size,
                              hipStream_t stream) {
  const float* x    = (const float*)d_in[0];
  const float* koop = (const float*)d_in[1];
  const float* sW1 = (const float*)d_in[2];  const float* sb1 = (const float*)d_in[3];
  const float* sW2 = (const float*)d_in[4];  const float* sb2 = (const float*)d_in[5];
  const float* sW3 = (const float*)d_in[6];  const float* sb3 = (const float*)d_in[7];
  const float* sW4 = (const float*)d_in[8];  const float* sb4 = (const float*)d_in[9];
  const float* tW1 = (const float*)d_in[10]; const float* tb1 = (const float*)d_in[11];
  const float* tW2 = (const float*)d_in[12]; const float* tb2 = (const float*)d_in[13];
  const float* tW3 = (const float*)d_in[14]; const float* tb3 = (const float*)d_in[15];
  const float* tW4 = (const float*)d_in[16]; const float* tb4 = (const float*)d_in[17];
  float* out = (float*)d_out;

  // Launch-invariant branch (ws_size constant across calls) -> graph-safe.
  // NEVER write past ws_size (R1: OOB pack corrupted harness allocations).
  if (ws_size >= (size_t)WPACK_BYTES) {
    f16* wpack = (f16*)d_ws;
    pack_weights<<<4608, 256, 0, stream>>>(sW1, sW2, sW3, sW4, tW1, tW2, tW3, tW4, wpack);
    decoder_main<true><<<2048, 512, 0, stream>>>(
        x, koop, wpack, sW1, sW2, sW3, sW4, tW1, tW2, tW3, tW4,
        sb1, sb2, sb3, sb4, tb1, tb2, tb3, tb4, out);
  } else {
    decoder_main<false><<<2048, 512, 0, stream>>>(
        x, koop, (const f16*)0, sW1, sW2, sW3, sW4, tW1, tW2, tW3, tW4,
        sb1, sb2, sb3, sb4, tb1, tb2, tb3, tb4, out);
  }
}